// Round 1
// 369.852 us; speedup vs baseline: 1.0320x; 1.0320x over previous
//
#include <hip/hip_runtime.h>
#include <stdint.h>

// Llama attention block, bf16 MFMA pipeline.
// B=2 S=2048 D=2048 NH=16 NKV=4 HD=128
#define B_    2
#define S_    2048
#define D_    2048
#define NH_   16
#define NKV_  4
#define HD_   128
#define M_    (B_*S_)     // 4096 rows
#define NQKV_ 3072        // NH*HD + 2*NKV*HD

typedef __bf16 bf16x8 __attribute__((ext_vector_type(8)));
typedef float  f32x4  __attribute__((ext_vector_type(4)));

__device__ __forceinline__ unsigned short f2bf(float f) {
    unsigned int u = __float_as_uint(f);
    u += 0x7fffu + ((u >> 16) & 1u);   // round-to-nearest-even
    return (unsigned short)(u >> 16);
}

// async global->LDS, 16B per lane; LDS dest = wave-uniform base + lane*16
__device__ __forceinline__ void async_cp16(const unsigned short* g, unsigned short* l) {
    __builtin_amdgcn_global_load_lds((const __attribute__((address_space(1))) void*)g,
                                     (__attribute__((address_space(3))) void*)l, 16, 0, 0);
}

// ---- cast x (fp32) -> bf16, 4 elems/thread ----
__global__ void cast_x(const float* __restrict__ x, unsigned short* __restrict__ xb) {
    int idx = blockIdx.x * 256 + threadIdx.x;
    float4 v = ((const float4*)x)[idx];
    unsigned int lo = (unsigned int)f2bf(v.x) | ((unsigned int)f2bf(v.y) << 16);
    unsigned int hi = (unsigned int)f2bf(v.z) | ((unsigned int)f2bf(v.w) << 16);
    ((uint2*)xb)[idx] = make_uint2(lo, hi);
}

// ---- transpose fp32 [2048][ncols] -> bf16 [ncols][2048] (B^T layout for GEMM) ----
__global__ void transpose_cast(const float* __restrict__ src,
                               unsigned short* __restrict__ dst, int ncols) {
    __shared__ float tile[32][33];
    int tx = threadIdx.x, ty = threadIdx.y;
    int n0 = blockIdx.x * 32, k0 = blockIdx.y * 32;
#pragma unroll
    for (int i = 0; i < 4; i++) {
        int k = k0 + ty + i * 8;
        tile[ty + i * 8][tx] = src[(long)k * ncols + n0 + tx];
    }
    __syncthreads();
#pragma unroll
    for (int i = 0; i < 4; i++) {
        int n = n0 + ty + i * 8;
        dst[(long)n * 2048 + k0 + tx] = f2bf(tile[tx][ty + i * 8]);
    }
}

// ---- RoPE cos/sin table: ctab[s*64+i] = {cos(s*invf_i), sin(s*invf_i)} ----
__global__ void rope_tables(float2* __restrict__ ctab) {
    int gid = blockIdx.x * 256 + threadIdx.x;   // 2048*64 entries
    int s = gid >> 6, i = gid & 63;
    float inv = exp2f(-(float)i * 0.20762050593046014f);  // 10000^(-i/64)
    float ang = (float)s * inv;
    float sn, cs; sincosf(ang, &sn, &cs);
    ctab[gid] = make_float2(cs, sn);
}

// ============================================================================
// 256x256 8-phase GEMM core (m201 template, plain HIP).
// BM=BN=256, BK=64, 512 threads = 8 waves (2M x 4N), per-wave C = 128x64
// (rows {wm*64..+64} in each 128-row half; cols {wn*32..+32} in each half).
// LDS 128 KiB: A[2buf][2half][128][64] bf16 + B same. st_16x32 swizzle
// (byte ^= ((byte>>9)&1)<<5) applied as involution: linear LDS dest,
// pre-swizzled global source, swizzled ds_read (rule #21).
// Counted vmcnt(6) at phases 4/8 only; 3 half-tiles in flight (T4).
// ============================================================================

__device__ __forceinline__ bf16x8 lds_frag(const unsigned short* hb, int r, int ks, int quad) {
    int p = (r * 128 + ks * 64 + quad * 16) ^ ((r & 4) << 3);   // st_16x32 swizzle
    return *(const bf16x8*)((const char*)hb + p);
}

// stage one 128x64 bf16 half-tile: 16 chunks of 1KB; chunk = wid*2+i.
// LDS dest linear; global source address pre-swizzled (same involution).
__device__ __forceinline__ void stage_half(const unsigned short* g, int Kel,
                                           unsigned short* lhalf, int wid, int lane) {
#pragma unroll
    for (int i = 0; i < 2; i++) {
        int chunk = wid * 2 + i;
        int o = chunk * 1024 + lane * 16;          // linear byte offset in half
        int row = o >> 7;
        int cb = (o & 127) ^ ((row & 4) << 3);     // inverse-swizzled source col
        async_cp16((const unsigned short*)((const char*)g + (size_t)row * Kel * 2 + cb),
                   lhalf + chunk * 512);
    }
}

// barrier; lgkmcnt(0); setprio(1); 16 MFMA (one C-quadrant x K=64); setprio(0); barrier
template<int MB, int NB>
__device__ __forceinline__ void cluster(f32x4 (*acc)[4], bf16x8 (*a)[2], bf16x8 (*b)[2]) {
    __builtin_amdgcn_sched_barrier(0);
    __builtin_amdgcn_s_barrier();
    asm volatile("s_waitcnt lgkmcnt(0)" ::: "memory");
    __builtin_amdgcn_sched_barrier(0);          // rule #18: pin MFMA after the wait
    __builtin_amdgcn_s_setprio(1);
#pragma unroll
    for (int ks = 0; ks < 2; ks++)
#pragma unroll
        for (int mi = 0; mi < 4; mi++)
#pragma unroll
            for (int ni = 0; ni < 2; ni++)
                acc[MB + mi][NB + ni] = __builtin_amdgcn_mfma_f32_16x16x32_bf16(
                    a[mi][ks], b[ni][ks], acc[MB + mi][NB + ni], 0, 0, 0);
    __builtin_amdgcn_s_setprio(0);
    __builtin_amdgcn_sched_barrier(0);
    __builtin_amdgcn_s_barrier();
    __builtin_amdgcn_sched_barrier(0);
}

__device__ __forceinline__ void gemm256_core(const unsigned short* __restrict__ A,
                                             const unsigned short* __restrict__ Bt,
                                             const int K, const int m0, const int n0,
                                             char* sm, f32x4 (*acc)[4]) {
    const int tid  = threadIdx.x;
    const int lane = tid & 63, wid = tid >> 6;
    const int quad = lane >> 4, l16 = lane & 15;
    const int wm = wid >> 2, wn = wid & 3;

    unsigned short* sA00 = (unsigned short*)(sm);            // buf0 half0 (rows 0-127)
    unsigned short* sA01 = (unsigned short*)(sm + 16384);    // buf0 half1 (rows 128-255)
    unsigned short* sA10 = (unsigned short*)(sm + 32768);    // buf1 half0
    unsigned short* sA11 = (unsigned short*)(sm + 49152);    // buf1 half1
    unsigned short* sB00 = (unsigned short*)(sm + 65536);
    unsigned short* sB01 = (unsigned short*)(sm + 81920);
    unsigned short* sB10 = (unsigned short*)(sm + 98304);
    unsigned short* sB11 = (unsigned short*)(sm + 114688);

    const unsigned short* A0 = A  + (size_t)m0 * K;
    const unsigned short* A1 = A  + (size_t)(m0 + 128) * K;
    const unsigned short* B0 = Bt + (size_t)n0 * K;
    const unsigned short* B1 = Bt + (size_t)(n0 + 128) * K;

    // prologue: tile0 all 4 halves (must retire), then tile1 {Ah0,Bh1,Ah1} (may fly)
    stage_half(A0,      K, sA00, wid, lane);
    stage_half(B1,      K, sB01, wid, lane);
    stage_half(A1,      K, sA01, wid, lane);
    stage_half(B0,      K, sB00, wid, lane);
    __builtin_amdgcn_sched_barrier(0);          // pin issue-order grouping for vmcnt math
    stage_half(A0 + 64, K, sA10, wid, lane);
    stage_half(B1 + 64, K, sB11, wid, lane);
    stage_half(A1 + 64, K, sA11, wid, lane);
    asm volatile("s_waitcnt vmcnt(6)" ::: "memory");   // retire tile0 (8 oldest loads)
    __builtin_amdgcn_sched_barrier(0);
    __builtin_amdgcn_s_barrier();
    __builtin_amdgcn_sched_barrier(0);

    const int NIT = K >> 7;                     // 2 K-tiles (BK=64) per iteration
    for (int j = 0; j < NIT; ++j) {
        const bool st = (j < NIT - 1);
        const int kof1 = (2 * j + 1) * 64;
        const int kof2 = (2 * j + 2) * 64;
        const int kof3 = (2 * j + 3) * 64;
        bf16x8 af[4][2], bA[2][2], bB[2][2];

        // ---- phase 1: tile 2j (buf0) quadrant (mlow,nlow); stage Bh0(2j+1)
#pragma unroll
        for (int mi = 0; mi < 4; mi++)
#pragma unroll
            for (int ks = 0; ks < 2; ks++)
                af[mi][ks] = lds_frag(sA00, wm * 64 + mi * 16 + l16, ks, quad);
#pragma unroll
        for (int ni = 0; ni < 2; ni++)
#pragma unroll
            for (int ks = 0; ks < 2; ks++)
                bA[ni][ks] = lds_frag(sB00, wn * 32 + ni * 16 + l16, ks, quad);
        stage_half(B0 + kof1, K, sB10, wid, lane);
        cluster<0, 0>(acc, af, bA);

        // ---- phase 2: (mlow,nhigh); stage Ah0(2j+2)
#pragma unroll
        for (int ni = 0; ni < 2; ni++)
#pragma unroll
            for (int ks = 0; ks < 2; ks++)
                bB[ni][ks] = lds_frag(sB01, wn * 32 + ni * 16 + l16, ks, quad);
        if (st) stage_half(A0 + kof2, K, sA00, wid, lane);
        cluster<0, 2>(acc, af, bB);

        // ---- phase 3: (mhigh,nhigh); stage Bh1(2j+2)
#pragma unroll
        for (int mi = 0; mi < 4; mi++)
#pragma unroll
            for (int ks = 0; ks < 2; ks++)
                af[mi][ks] = lds_frag(sA01, wm * 64 + mi * 16 + l16, ks, quad);
        if (st) stage_half(B1 + kof2, K, sB01, wid, lane);
        cluster<4, 2>(acc, af, bB);

        // ---- phase 4: (mhigh,nlow); stage Ah1(2j+2); vmcnt
#pragma unroll
        for (int ni = 0; ni < 2; ni++)
#pragma unroll
            for (int ks = 0; ks < 2; ks++)
                bA[ni][ks] = lds_frag(sB00, wn * 32 + ni * 16 + l16, ks, quad);
        if (st) {
            stage_half(A1 + kof2, K, sA01, wid, lane);
            asm volatile("s_waitcnt vmcnt(6)" ::: "memory");
        } else {
            asm volatile("s_waitcnt vmcnt(0)" ::: "memory");   // drain (last iter)
        }
        cluster<4, 0>(acc, af, bA);

        // ---- phase 5: tile 2j+1 (buf1) (mlow,nlow); stage Bh0(2j+2)
#pragma unroll
        for (int mi = 0; mi < 4; mi++)
#pragma unroll
            for (int ks = 0; ks < 2; ks++)
                af[mi][ks] = lds_frag(sA10, wm * 64 + mi * 16 + l16, ks, quad);
#pragma unroll
        for (int ni = 0; ni < 2; ni++)
#pragma unroll
            for (int ks = 0; ks < 2; ks++)
                bA[ni][ks] = lds_frag(sB10, wn * 32 + ni * 16 + l16, ks, quad);
        if (st) stage_half(B0 + kof2, K, sB00, wid, lane);
        cluster<0, 0>(acc, af, bA);

        // ---- phase 6: (mlow,nhigh); stage Ah0(2j+3)
#pragma unroll
        for (int ni = 0; ni < 2; ni++)
#pragma unroll
            for (int ks = 0; ks < 2; ks++)
                bB[ni][ks] = lds_frag(sB11, wn * 32 + ni * 16 + l16, ks, quad);
        if (st) stage_half(A0 + kof3, K, sA10, wid, lane);
        cluster<0, 2>(acc, af, bB);

        // ---- phase 7: (mhigh,nhigh); stage Bh1(2j+3)
#pragma unroll
        for (int mi = 0; mi < 4; mi++)
#pragma unroll
            for (int ks = 0; ks < 2; ks++)
                af[mi][ks] = lds_frag(sA11, wm * 64 + mi * 16 + l16, ks, quad);
        if (st) stage_half(B1 + kof3, K, sB11, wid, lane);
        cluster<4, 2>(acc, af, bB);

        // ---- phase 8: (mhigh,nlow); stage Ah1(2j+3); vmcnt
#pragma unroll
        for (int ni = 0; ni < 2; ni++)
#pragma unroll
            for (int ks = 0; ks < 2; ks++)
                bA[ni][ks] = lds_frag(sB10, wn * 32 + ni * 16 + l16, ks, quad);
        if (st) {
            stage_half(A1 + kof3, K, sA11, wid, lane);
            asm volatile("s_waitcnt vmcnt(6)" ::: "memory");
        }
        cluster<4, 0>(acc, af, bA);
    }
}

// ---- QKV GEMM (256^2 8-phase) with fused RoPE epilogue ----
// n-blocks are Q/K/V-homogeneous: bx<8 -> Q, bx in {8,9} -> K, bx in {10,11} -> V.
__global__ __launch_bounds__(512, 2) void gemm_qkv256(const unsigned short* __restrict__ A,
                                                      const unsigned short* __restrict__ Bt,
                                                      const float2* __restrict__ ctab,
                                                      unsigned short* __restrict__ Qr,
                                                      unsigned short* __restrict__ Kr,
                                                      unsigned short* __restrict__ Vrow) {
    extern __shared__ char sm[];
    const int m0 = blockIdx.y * 256, n0 = blockIdx.x * 256;
    f32x4 acc[8][4] = {};
    gemm256_core(A, Bt, D_, m0, n0, sm, acc);

    const int tid  = threadIdx.x;
    const int lane = tid & 63, wid = tid >> 6;
    const int quad = lane >> 4, l16 = lane & 15;
    const int wm = wid >> 2, wn = wid & 3;

    if (n0 < 2048) {            // Q + RoPE
#pragma unroll
        for (int mt = 0; mt < 8; mt++) {
            int rowb = m0 + ((mt & 4) << 5) + wm * 64 + (mt & 3) * 16 + quad * 4;
#pragma unroll
            for (int nt = 0; nt < 4; nt++) {
                int col = n0 + ((nt & 2) << 6) + wn * 32 + (nt & 1) * 16 + l16;
                int h = col >> 7, d = col & 127;
#pragma unroll
                for (int r = 0; r < 4; r++) {
                    int row = rowb + r;
                    int s = row & 2047, b = row >> 11;
                    float2 cs = ctab[s * 64 + (d >> 1)];
                    float own = acc[mt][nt][r];
                    float other = __shfl_xor(own, 1);
                    float val = (d & 1) ? (other * cs.y + own * cs.x)
                                        : (own * cs.x - other * cs.y);
                    Qr[((size_t)(b * 16 + h) * 2048 + s) * 128 + d] = f2bf(val);
                }
            }
        }
    } else if (n0 < 2560) {     // K + RoPE
#pragma unroll
        for (int mt = 0; mt < 8; mt++) {
            int rowb = m0 + ((mt & 4) << 5) + wm * 64 + (mt & 3) * 16 + quad * 4;
#pragma unroll
            for (int nt = 0; nt < 4; nt++) {
                int col = n0 + ((nt & 2) << 6) + wn * 32 + (nt & 1) * 16 + l16;
                int kvh = (col - 2048) >> 7, d = col & 127;
#pragma unroll
                for (int r = 0; r < 4; r++) {
                    int row = rowb + r;
                    int s = row & 2047, b = row >> 11;
                    float2 cs = ctab[s * 64 + (d >> 1)];
                    float own = acc[mt][nt][r];
                    float other = __shfl_xor(own, 1);
                    float val = (d & 1) ? (other * cs.y + own * cs.x)
                                        : (own * cs.x - other * cs.y);
                    Kr[((size_t)(b * 4 + kvh) * 2048 + s) * 128 + d] = f2bf(val);
                }
            }
        }
    } else {                    // V: bf16 row-major staging [4096][512]
#pragma unroll
        for (int mt = 0; mt < 8; mt++) {
            int rowb = m0 + ((mt & 4) << 5) + wm * 64 + (mt & 3) * 16 + quad * 4;
#pragma unroll
            for (int nt = 0; nt < 4; nt++) {
                int col = n0 + ((nt & 2) << 6) + wn * 32 + (nt & 1) * 16 + l16;
#pragma unroll
                for (int r = 0; r < 4; r++)
                    Vrow[(size_t)(rowb + r) * 512 + (col - 2560)] = f2bf(acc[mt][nt][r]);
            }
        }
    }
}

// ---- output projection GEMM (256^2 8-phase): C fp32 [4096][2048] = attn @ Wo^T ----
__global__ __launch_bounds__(512, 2) void gemm_bt256(const unsigned short* __restrict__ A,
                                                     const unsigned short* __restrict__ Bt,
                                                     float* __restrict__ C) {
    extern __shared__ char sm[];
    const int m0 = blockIdx.y * 256, n0 = blockIdx.x * 256;
    f32x4 acc[8][4] = {};
    gemm256_core(A, Bt, NH_ * HD_, m0, n0, sm, acc);

    const int tid  = threadIdx.x;
    const int lane = tid & 63, wid = tid >> 6;
    const int quad = lane >> 4, l16 = lane & 15;
    const int wm = wid >> 2, wn = wid & 3;
#pragma unroll
    for (int mt = 0; mt < 8; mt++) {
        int rowb = m0 + ((mt & 4) << 5) + wm * 64 + (mt & 3) * 16 + quad * 4;
#pragma unroll
        for (int nt = 0; nt < 4; nt++) {
            int col = n0 + ((nt & 2) << 6) + wn * 32 + (nt & 1) * 16 + l16;
#pragma unroll
            for (int r = 0; r < 4; r++)
                C[(size_t)(rowb + r) * 2048 + col] = acc[mt][nt][r];
        }
    }
}

// ---- V transpose (bf16): Vrow [4096][512] -> Vt [B][NKV][HD][S] ----
__global__ void v_trans_bf(const unsigned short* __restrict__ Vrow,
                           unsigned short* __restrict__ Vt) {
    __shared__ unsigned short tile[32][34];
    int tx = threadIdx.x, ty = threadIdx.y;
    int s0 = blockIdx.x * 32, d0 = blockIdx.y * 32;
    int bz = blockIdx.z;                       // b*NKV + kvh
    int b = bz >> 2, kvh = bz & 3;
#pragma unroll
    for (int i = 0; i < 4; i++) {
        int s = s0 + ty + i * 8;
        tile[ty + i * 8][tx] = Vrow[(long)(b * 2048 + s) * 512 + kvh * 128 + d0 + tx];
    }
    __syncthreads();
#pragma unroll
    for (int i = 0; i < 4; i++) {
        int d = d0 + ty + i * 8;
        Vt[((long)bz * 128 + d) * 2048 + s0 + tx] = tile[tx][ty + i * 8];
    }
}

// ---- Flash attention: causal, GQA. (unchanged this round) ----
__global__ __launch_bounds__(256) void attn_fwd(const unsigned short* __restrict__ Qr,
                                                const unsigned short* __restrict__ Kr,
                                                const unsigned short* __restrict__ Vt,
                                                unsigned short* __restrict__ O) {
    __shared__ unsigned short Ks[64][136];    // kv x hd (+8 pad)
    __shared__ unsigned short Vs[128][72];    // hd x kv (+8 pad)
    __shared__ unsigned short Ps[4][16][72];  // per-wave P (wave-private)
    const int tid  = threadIdx.x;
    const int lane = tid & 63, wid = tid >> 6;
    const int quad = lane >> 4, l16 = lane & 15;
    const int pid = blockIdx.x, h = blockIdx.y, b = blockIdx.z;
    const int kvh = h >> 2;                   // NH/NKV = 4
    const unsigned short* qp = Qr + (long)(b * NH_ + h) * S_ * HD_;
    const unsigned short* kp = Kr + (long)(b * NKV_ + kvh) * S_ * HD_;
    const unsigned short* vp = Vt + (long)(b * NKV_ + kvh) * HD_ * S_;
    const float sc2 = 0.08838834764831845f * 1.4426950408889634f;  // scale*log2e

    bf16x8 ones;
#pragma unroll
    for (int i = 0; i < 8; i++) ones[i] = (__bf16)1.0f;

    for (int phase = 0; phase < 2; phase++) {
        const int qt = phase ? pid : 31 - pid;    // heavy strip first
        const int qw = qt * 64 + wid * 16;        // this wave's 16 q rows

        bf16x8 aq[4];
#pragma unroll
        for (int ks = 0; ks < 4; ks++)
            aq[ks] = *(const bf16x8*)&qp[(long)(qw + l16) * HD_ + ks * 32 + quad * 8];

        f32x4 o[8] = {};
        float mi[4], li[4];
#pragma unroll
        for (int r = 0; r < 4; r++) { mi[r] = -3.0e38f; li[r] = 0.f; }

        for (int kt = 0; kt <= qt; kt++) {
            const int kv0 = kt * 64;
            __syncthreads();
#pragma unroll
            for (int i = 0; i < 4; i++) {        // stage K tile: 64 x 128
                int idx = tid + i * 256;
                int row = idx >> 4, c = (idx & 15) * 8;
                *(uint4*)&Ks[row][c] = *(const uint4*)&kp[(long)(kv0 + row) * HD_ + c];
            }
#pragma unroll
            for (int i = 0; i < 4; i++) {        // stage V^T tile: 128 x 64
                int idx = tid + i * 256;
                int hd = idx >> 3, c = (idx & 7) * 8;
                *(uint4*)&Vs[hd][c] = *(const uint4*)&vp[(long)hd * S_ + kv0 + c];
            }
            __syncthreads();

            // S = Q K^T (16 x 64 per wave)
            f32x4 s[4] = {};
#pragma unroll
            for (int ks = 0; ks < 4; ks++)
#pragma unroll
                for (int nt = 0; nt < 4; nt++) {
                    bf16x8 kb = *(const bf16x8*)&Ks[nt * 16 + l16][ks * 32 + quad * 8];
                    s[nt] = __builtin_amdgcn_mfma_f32_16x16x32_bf16(aq[ks], kb, s[nt], 0, 0, 0);
                }

            // online softmax in exp2 domain (row max via shfl; sum via MFMA below)
            float mt[4];
#pragma unroll
            for (int r = 0; r < 4; r++) mt[r] = -3.0e38f;
            if (kv0 + 63 > qw) {                 // diagonal tile: causal mask
#pragma unroll
                for (int nt = 0; nt < 4; nt++) {
                    int kvp = kv0 + nt * 16 + l16;
#pragma unroll
                    for (int r = 0; r < 4; r++) {
                        float sv = s[nt][r] * sc2;
                        sv = (kvp <= qw + quad * 4 + r) ? sv : -1.0e30f;
                        s[nt][r] = sv;
                        mt[r] = fmaxf(mt[r], sv);
                    }
                }
            } else {
#pragma unroll
                for (int nt = 0; nt < 4; nt++)
#pragma unroll
                    for (int r = 0; r < 4; r++) {
                        float sv = s[nt][r] * sc2;
                        s[nt][r] = sv;
                        mt[r] = fmaxf(mt[r], sv);
                    }
            }
#pragma unroll
            for (int off = 1; off < 16; off <<= 1)
#pragma unroll
                for (int r = 0; r < 4; r++)
                    mt[r] = fmaxf(mt[r], __shfl_xor(mt[r], off));
            float al[4];
#pragma unroll
            for (int r = 0; r < 4; r++) {
                float mn = fmaxf(mi[r], mt[r]);
                al[r] = exp2f(mi[r] - mn);
                mi[r] = mn;
            }
#pragma unroll
            for (int nt = 0; nt < 4; nt++)
#pragma unroll
                for (int r = 0; r < 4; r++)
                    s[nt][r] = exp2f(s[nt][r] - mi[r]);
#pragma unroll
            for (int t = 0; t < 8; t++)
#pragma unroll
                for (int r = 0; r < 4; r++) o[t][r] *= al[r];

            // P: C-layout -> wave-private LDS -> A-layout (no barrier)
#pragma unroll
            for (int nt = 0; nt < 4; nt++)
#pragma unroll
                for (int r = 0; r < 4; r++)
                    Ps[wid][quad * 4 + r][nt * 16 + l16] = f2bf(s[nt][r]);

            // O += P V; row-sums of P via MFMA with all-ones B (layout-free)
            f32x4 sumf = {};
#pragma unroll
            for (int ks2 = 0; ks2 < 2; ks2++) {
                bf16x8 pa = *(const bf16x8*)&Ps[wid][l16][ks2 * 32 + quad * 8];
                sumf = __builtin_amdgcn_mfma_f32_16x16x32_bf16(pa, ones, sumf, 0, 0, 0);
#pragma unroll
                for (int vt = 0; vt < 8; vt++) {
                    bf16x8 vb = *(const bf16x8*)&Vs[vt * 16 + l16][ks2 * 32 + quad * 8];
                    o[vt] = __builtin_amdgcn_mfma_f32_16x16x32_bf16(pa, vb, o[vt], 0, 0, 0);
                }
            }
#pragma unroll
            for (int r = 0; r < 4; r++) li[r] = li[r] * al[r] + sumf[r];
        }

        // epilogue: O/l -> attn buffer bf16 [b*S+s][h*128+hd]
#pragma unroll
        for (int r = 0; r < 4; r++) {
            float inv_l = 1.0f / li[r];
            int qpos = qw + quad * 4 + r;
#pragma unroll
            for (int vt = 0; vt < 8; vt++) {
                float val = o[vt][r] * inv_l;
                O[(long)(b * S_ + qpos) * 2048 + h * 128 + vt * 16 + l16] = f2bf(val);
            }
        }
    }
}

extern "C" void kernel_launch(void* const* d_in, const int* in_sizes, int n_in,
                              void* d_out, int out_size, void* d_ws, size_t ws_size,
                              hipStream_t stream) {
    const float* x  = (const float*)d_in[0];
    // d_in[1] = mask: deterministic causal tril, applied analytically in attn_fwd.
    const float* Wq = (const float*)d_in[2];
    const float* Wk = (const float*)d_in[3];
    const float* Wv = (const float*)d_in[4];
    const float* Wo = (const float*)d_in[5];

    char* ws = (char*)d_ws;
    unsigned short* xb    = (unsigned short*)(ws);                 // 16,777,216 B
    unsigned short* Wqkvt = (unsigned short*)(ws + 16777216);      // 12,582,912 B
    unsigned short* Wot   = (unsigned short*)(ws + 29360128);      //  8,388,608 B
    float2*         ctab  = (float2*)        (ws + 37748736);      //  1,048,576 B
    unsigned short* Qr    = (unsigned short*)(ws + 38797312);      // 16,777,216 B
    unsigned short* Kr    = (unsigned short*)(ws + 55574528);      //  4,194,304 B
    unsigned short* Vrow  = (unsigned short*)(ws + 59768832);      //  4,194,304 B
    unsigned short* Vt    = (unsigned short*)(ws + 63963136);      //  4,194,304 B
    unsigned short* attn  = (unsigned short*)(ws + 68157440);      // 16,777,216 B

    static int attr_set = 0;
    if (!attr_set) {
        hipFuncSetAttribute(reinterpret_cast<const void*>(gemm_qkv256),
                            hipFuncAttributeMaxDynamicSharedMemorySize, 131072);
        hipFuncSetAttribute(reinterpret_cast<const void*>(gemm_bt256),
                            hipFuncAttributeMaxDynamicSharedMemorySize, 131072);
        attr_set = 1;
    }

    cast_x<<<8192, 256, 0, stream>>>(x, xb);
    dim3 tb(32, 8);
    transpose_cast<<<dim3(64, 64), tb, 0, stream>>>(Wq, Wqkvt, 2048);
    transpose_cast<<<dim3(16, 64), tb, 0, stream>>>(Wk, Wqkvt + 2048 * 2048, 512);
    transpose_cast<<<dim3(16, 64), tb, 0, stream>>>(Wv, Wqkvt + 2560 * 2048, 512);
    transpose_cast<<<dim3(64, 64), tb, 0, stream>>>(Wo, Wot, 2048);
    rope_tables<<<512, 256, 0, stream>>>(ctab);

    // QKV GEMM, 256^2 8-phase, fused RoPE/V-split epilogue. grid 12x16 = 192 blocks.
    gemm_qkv256<<<dim3(12, 16), 512, 131072, stream>>>(xb, Wqkvt, ctab, Qr, Kr, Vrow);

    v_trans_bf<<<dim3(64, 4, 8), tb, 0, stream>>>(Vrow, Vt);

    attn_fwd<<<dim3(16, NH_, B_), 256, 0, stream>>>(Qr, Kr, Vt, attn);

    // output projection, 256^2 8-phase. grid 8x16 = 128 blocks.
    gemm_bt256<<<dim3(8, 16), 512, 131072, stream>>>(attn, Wot, (float*)d_out);
}